// Round 9
// baseline (217.558 us; speedup 1.0000x reference)
//
#include <hip/hip_runtime.h>
#include <hip/hip_bf16.h>

#define BS   8192
#define DIM  768
#define BM   256
#define BN   128
#define BK   128   // one scaled-MFMA K per tile; 6 tiles total

typedef float f32x4 __attribute__((ext_vector_type(4)));
typedef int   i32x4 __attribute__((ext_vector_type(4)));
typedef int   i32x8 __attribute__((ext_vector_type(8)));

__device__ __forceinline__ void async16(const void* g, void* l) {
    __builtin_amdgcn_global_load_lds(
        (const __attribute__((address_space(1))) unsigned int*)g,
        (__attribute__((address_space(3))) unsigned int*)l,
        16, 0, 0);
}

// One wave per row: L2-norm both embeddings, emit fp8 e4m3, diag sim in fp32.
// Blocks 0..63 also zero rowsum/colsum (replaces the hipMemsetAsync dispatch).
__global__ __launch_bounds__(256) void normalize_kernel(
    const float* __restrict__ text, const float* __restrict__ ctr,
    unsigned char* __restrict__ tq, unsigned char* __restrict__ cq,
    float* __restrict__ sim, float* __restrict__ rowsum, float* __restrict__ colsum) {
    if (blockIdx.x < 64) {
        const int i = blockIdx.x * 256 + threadIdx.x;   // covers 16384 = 2*BS
        rowsum[i] = 0.f;
        colsum[i] = 0.f;
    }
    const int lane = threadIdx.x & 63;
    const int row  = blockIdx.x * 4 + (threadIdx.x >> 6);
    const size_t base = (size_t)row * DIM;

    float4 t[3], c[3];
    float st = 0.f, sc = 0.f, sd = 0.f;
#pragma unroll
    for (int i = 0; i < 3; ++i) {
        t[i] = *(const float4*)&text[base + lane * 4 + i * 256];
        c[i] = *(const float4*)&ctr [base + lane * 4 + i * 256];
        st += t[i].x*t[i].x + t[i].y*t[i].y + t[i].z*t[i].z + t[i].w*t[i].w;
        sc += c[i].x*c[i].x + c[i].y*c[i].y + c[i].z*c[i].z + c[i].w*c[i].w;
        sd += t[i].x*c[i].x + t[i].y*c[i].y + t[i].z*c[i].z + t[i].w*c[i].w;
    }
#pragma unroll
    for (int off = 1; off < 64; off <<= 1) {
        st += __shfl_xor(st, off);
        sc += __shfl_xor(sc, off);
        sd += __shfl_xor(sd, off);
    }
    const float invt = 1.0f / fmaxf(sqrtf(st), 1e-8f);
    const float invc = 1.0f / fmaxf(sqrtf(sc), 1e-8f);
#pragma unroll
    for (int i = 0; i < 3; ++i) {
        unsigned int wt = (unsigned int)__builtin_amdgcn_cvt_pk_fp8_f32(t[i].x * invt, t[i].y * invt, 0, false);
        wt = (unsigned int)__builtin_amdgcn_cvt_pk_fp8_f32(t[i].z * invt, t[i].w * invt, (int)wt, true);
        unsigned int wcq = (unsigned int)__builtin_amdgcn_cvt_pk_fp8_f32(c[i].x * invc, c[i].y * invc, 0, false);
        wcq = (unsigned int)__builtin_amdgcn_cvt_pk_fp8_f32(c[i].z * invc, c[i].w * invc, (int)wcq, true);
        *(unsigned int*)&tq[base + lane * 4 + i * 256] = wt;
        *(unsigned int*)&cq[base + lane * 4 + i * 256] = wcq;
    }
    if (lane == 0) sim[row] = sd * invt * invc;
}

// MX-scaled fp8 GEMM (unit scales) -- round 13: re-balance registers/LDS for
// 2 blocks/CU. R8 counters showed the deep-pipeline 256^2 kernel is resident
// at only 1 block/CU (OccupancyPercent 21): acc[8][4]=128 AGPR + 124 VGPR
// ~= 252 regs/wave -> 2 waves/SIMD, so there was ZERO inter-block overlap --
// and the session's consistent finding (R3 3blk/CU=107 vs R1/R2 1-2blk=118;
// guide m114/m148) is that inter-block TLP, not intra-block scheduling, hides
// the stage drain at short K (6 K-iters). New geometry: BM=256 BN=128,
// SINGLE-buffered LDS (32+16=48 KB), simple stage->sync->compute->sync loop,
// per-wave 128x32 -> acc[8][2] = 64 regs, launch_bounds(512,4) caps at 128
// regs/wave -> 16 waves/CU = 2 blocks/CU. Per-wave per K-tile: 16 MFMA vs
// 6 staged loads (better ratio than both R3 and R8). Numerics identical.
// LDS layout per operand: [kc(4)][row][32B], halves swizzled by (kc&1):
// conflict-free (same pattern as all rounds, SQ_LDS_BANK_CONFLICT=0).
__global__ __launch_bounds__(512, 4) void gemm_lse_kernel(
    const unsigned char* __restrict__ tq, const unsigned char* __restrict__ cq,
    float* __restrict__ rowsum, float* __restrict__ colsum) {
    __shared__ char ldsA[BM * BK];   // 32 KB
    __shared__ char ldsB[BN * BK];   // 16 KB

    const int tid = threadIdx.x;

    // XCD-banded swizzle: XCD x owns tile-row-bands [4x, 4x+4), sweeping cols.
    const int bid = blockIdx.x;              // 2048 blocks = 32 bands x 64 cols
    const int xcd = bid & 7, idx = bid >> 3;
    const int rowBase = (xcd * 4 + (idx & 3)) * BM;
    const int colBase = (idx >> 2) * BN;

    const int wave = tid >> 6, lane = tid & 63;
    const int wr = wave >> 2, wc = wave & 3;   // 2x4 wave grid: 128x32 per wave
    const int quad = lane >> 4, l16 = lane & 15;

    // Staging. A: 2048 16B chunks/tile (4/thread); B: 1024 (2/thread).
    // chunk p -> kc, row, logical-half hl = (p&1)^(kc&1); LDS dest linear.
    int goffA[4], pA[4];
#pragma unroll
    for (int i = 0; i < 4; ++i) {
        const int p  = tid + i * 512;
        const int kc = p >> 9;               // A: 512 chunks per kc block
        const int row = (p >> 1) & 255;
        const int hl  = (p & 1) ^ (kc & 1);
        goffA[i] = row * DIM + kc * 32 + hl * 16;
        pA[i]    = p * 16;
    }
    int goffB[2], pB[2];
#pragma unroll
    for (int i = 0; i < 2; ++i) {
        const int p  = tid + i * 512;
        const int kc = p >> 8;               // B: 256 chunks per kc block
        const int row = (p >> 1) & 127;
        const int hl  = (p & 1) ^ (kc & 1);
        goffB[i] = row * DIM + kc * 32 + hl * 16;
        pB[i]    = p * 16;
    }
    const unsigned char* gA = tq + (size_t)rowBase * DIM;
    const unsigned char* gB = cq + (size_t)colBase * DIM;

    // Fragment addressing: lane (quad,l16) needs k-block kc=quad of its row;
    // physical half = logical half ^ (quad&1).
    const int sw = quad & 1;
    const int abase = quad * 8192 + (wr * 128 + l16) * 32;  // + mt*512
    const int bbase = quad * 4096 + (wc * 32  + l16) * 32;  // + nt*512

    f32x4 acc[8][2];
#pragma unroll
    for (int mt = 0; mt < 8; ++mt)
#pragma unroll
        for (int nt = 0; nt < 2; ++nt)
            acc[mt][nt] = (f32x4){0.f, 0.f, 0.f, 0.f};

    for (int t = 0; t < 6; ++t) {
        const int k0 = t * BK;
#pragma unroll
        for (int i = 0; i < 4; ++i) async16(gA + goffA[i] + k0, ldsA + pA[i]);
#pragma unroll
        for (int i = 0; i < 2; ++i) async16(gB + goffB[i] + k0, ldsB + pB[i]);
        __syncthreads();   // implicit vmcnt(0): tile staged

        i32x8 bf[2];
#pragma unroll
        for (int nt = 0; nt < 2; ++nt) {
            i32x4 lo = *(const i32x4*)(ldsB + bbase + nt * 512 + sw * 16);
            i32x4 hi = *(const i32x4*)(ldsB + bbase + nt * 512 + (sw ^ 1) * 16);
            bf[nt] = __builtin_shufflevector(lo, hi, 0, 1, 2, 3, 4, 5, 6, 7);
        }
#pragma unroll
        for (int mt = 0; mt < 8; ++mt) {
            i32x4 lo = *(const i32x4*)(ldsA + abase + mt * 512 + sw * 16);
            i32x4 hi = *(const i32x4*)(ldsA + abase + mt * 512 + (sw ^ 1) * 16);
            i32x8 af = __builtin_shufflevector(lo, hi, 0, 1, 2, 3, 4, 5, 6, 7);
            acc[mt][0] = __builtin_amdgcn_mfma_scale_f32_16x16x128_f8f6f4(
                af, bf[0], acc[mt][0], 0, 0, 0, 127, 0, 127);
            acc[mt][1] = __builtin_amdgcn_mfma_scale_f32_16x16x128_f8f6f4(
                af, bf[1], acc[mt][1], 0, 0, 0, 127, 0, 127);
        }
        __syncthreads();   // reads done before next tile overwrites
    }

    // Epilogue. D layout: col = l16 (ctr idx), row = quad*4 + reg (text idx).
    float rp[8][4];   // [mt][reg] partials over this wave's 32 cols
    float cp[2];      // [nt] partials over this wave's 128 rows
#pragma unroll
    for (int mt = 0; mt < 8; ++mt)
#pragma unroll
        for (int r = 0; r < 4; ++r) rp[mt][r] = 0.f;
#pragma unroll
    for (int nt = 0; nt < 2; ++nt) cp[nt] = 0.f;

#pragma unroll
    for (int mt = 0; mt < 8; ++mt)
#pragma unroll
        for (int nt = 0; nt < 2; ++nt)
#pragma unroll
            for (int r = 0; r < 4; ++r) {
                const float e = __expf(acc[mt][nt][r]);   // S in [-1,1]: no max needed
                rp[mt][r] += e;
                cp[nt]    += e;
            }

#pragma unroll
    for (int mt = 0; mt < 8; ++mt)
#pragma unroll
        for (int r = 0; r < 4; ++r) {
            float v = rp[mt][r];
            v += __shfl_xor(v, 1);
            v += __shfl_xor(v, 2);
            v += __shfl_xor(v, 4);
            v += __shfl_xor(v, 8);
            rp[mt][r] = v;
        }
    if (l16 == 0) {
#pragma unroll
        for (int mt = 0; mt < 8; ++mt)
#pragma unroll
            for (int r = 0; r < 4; ++r)
                atomicAdd(&rowsum[rowBase + wr * 128 + mt * 16 + quad * 4 + r], rp[mt][r]);
    }
#pragma unroll
    for (int nt = 0; nt < 2; ++nt) {
        float v = cp[nt];
        v += __shfl_xor(v, 16);
        v += __shfl_xor(v, 32);
        if (quad == 0)
            atomicAdd(&colsum[colBase + wc * 32 + nt * 16 + l16], v);
    }
}

__global__ __launch_bounds__(1024) void finalize_kernel(
    const float* __restrict__ rowsum, const float* __restrict__ colsum,
    const float* __restrict__ sim, float* __restrict__ out) {
    const int tid = threadIdx.x;
    float acc = 0.f;
#pragma unroll
    for (int i = 0; i < 2; ++i) {
        const int j = (tid + i * 1024) * 4;
        float4 rs = *(const float4*)&rowsum[j];
        float4 cs = *(const float4*)&colsum[j];
        float4 sm = *(const float4*)&sim[j];
        acc += __logf(rs.x) + __logf(rs.y) + __logf(rs.z) + __logf(rs.w);
        acc += __logf(cs.x) + __logf(cs.y) + __logf(cs.z) + __logf(cs.w);
        acc -= 2.f * (sm.x + sm.y + sm.z + sm.w);
    }
#pragma unroll
    for (int off = 1; off < 64; off <<= 1) acc += __shfl_xor(acc, off);
    __shared__ float red[16];
    const int wave = tid >> 6, lane = tid & 63;
    if (lane == 0) red[wave] = acc;
    __syncthreads();
    if (tid == 0) {
        float s = 0.f;
#pragma unroll
        for (int w = 0; w < 16; ++w) s += red[w];
        out[0] = s / (float)BS;
    }
}

extern "C" void kernel_launch(void* const* d_in, const int* in_sizes, int n_in,
                              void* d_out, int out_size, void* d_ws, size_t ws_size,
                              hipStream_t stream) {
    const float* text = (const float*)d_in[0];
    const float* ctr  = (const float*)d_in[1];

    char* ws = (char*)d_ws;
    const size_t embBytes = (size_t)BS * DIM;   // fp8: 6,291,456 bytes each
    unsigned char* tq = (unsigned char*)ws;
    unsigned char* cq = (unsigned char*)(ws + embBytes);
    float* sim    = (float*)(ws + 2 * embBytes);
    float* rowsum = (float*)(ws + 2 * embBytes + BS * sizeof(float));
    float* colsum = (float*)(ws + 2 * embBytes + 2 * BS * sizeof(float));

    normalize_kernel<<<BS / 4, 256, 0, stream>>>(text, ctr, tq, cq, sim, rowsum, colsum);

    gemm_lse_kernel<<<(BS / BM) * (BS / BN), 512, 0, stream>>>(tq, cq, rowsum, colsum);

    finalize_kernel<<<1, 1024, 0, stream>>>(rowsum, colsum, sim, (float*)d_out);
}